// Round 7
// baseline (272.307 us; speedup 1.0000x reference)
//
#include <hip/hip_runtime.h>
#include <hip/hip_bf16.h>

// ---------------------------------------------------------------------------
// MHA forward, bf16 MFMA.
//   wt_prep_all      : 4 W fp32 -> Wt bf16 transposed [e][d]
//   gemm_qkv (z=0..2): q/k/v @ Wt + b -> Qh/Kh head-major; z==2 writes
//                      Vtp[bh][d][s'] DIRECTLY (PV permutation baked)
//   attn_mfma        : flash attn, no-max softmax, split-K, register-dieted
//                      (per-kt S, VALU l-accum, launch_bounds(256,4))
//   gemm_out         : Xp @ WtO + bo -> out fp32 (global_load_lds staging)
// ---------------------------------------------------------------------------

typedef __attribute__((ext_vector_type(8))) short bf16x8;   // 8 bf16 = 4 VGPR
typedef __attribute__((ext_vector_type(4))) float f32x4;    // MFMA acc

constexpr int SEQ   = 2048;
constexpr int BATCH = 2;
constexpr int DM    = 1024;
constexpr int DK    = 64;
constexpr int MR    = SEQ * BATCH;    // 4096 GEMM rows
constexpr int SST   = BATCH * DM;     // 2048 shorts per s-step in std layout
constexpr int HD    = SEQ * DK;       // 131072 shorts per (b,h) head-major

__device__ __forceinline__ unsigned pkbf(float a, float b) {
    __hip_bfloat162 h = __float22bfloat162_rn(float2{a, b});
    union { __hip_bfloat162 h2; unsigned u; } cv;
    cv.h2 = h;
    return cv.u;
}

__device__ __forceinline__ f32x4 mfma16(bf16x8 a, bf16x8 b, f32x4 c) {
    return __builtin_amdgcn_mfma_f32_16x16x32_bf16(a, b, c, 0, 0, 0);
}

// async global->LDS, 16B per lane; lds base must be wave-uniform
__device__ __forceinline__ void gl16(const unsigned short* g, unsigned short* l) {
    __builtin_amdgcn_global_load_lds(
        (const __attribute__((address_space(1))) void*)g,
        (__attribute__((address_space(3))) void*)l, 16, 0, 0);
}

// ---------------------------------------------------------------------------
// wt_prep_all: Wt[e][d] = bf16(W[d][e]) for all 4 weight matrices.
// grid (16, 4, 4), 256 threads.
// ---------------------------------------------------------------------------
__global__ __launch_bounds__(256)
void wt_prep_all(const float* __restrict__ w0, const float* __restrict__ w1,
                 const float* __restrict__ w2, const float* __restrict__ w3,
                 unsigned short* __restrict__ o0, unsigned short* __restrict__ o1,
                 unsigned short* __restrict__ o2, unsigned short* __restrict__ o3)
{
    const int z = blockIdx.z;
    const float* W = (z == 0) ? w0 : (z == 1) ? w1 : (z == 2) ? w2 : w3;
    unsigned short* Wt = (z == 0) ? o0 : (z == 1) ? o1 : (z == 2) ? o2 : o3;

    const int t = threadIdx.x;
    const int e = blockIdx.x * 64 + (t & 63);
    const int dq = blockIdx.y * 256 + (t >> 6) * 64;
    unsigned short* orow = Wt + (size_t)e * DM + dq;
#pragma unroll
    for (int c = 0; c < 8; ++c) {
        float f[8];
#pragma unroll
        for (int j = 0; j < 8; ++j)
            f[j] = W[(size_t)(dq + c * 8 + j) * DM + e];
        uint4 u = { pkbf(f[0], f[1]), pkbf(f[2], f[3]),
                    pkbf(f[4], f[5]), pkbf(f[6], f[7]) };
        *(uint4*)(orow + c * 8) = u;
    }
}

// ---------------------------------------------------------------------------
// gemm_qkv: C = A[4096][1024] @ Wt^T + bias. A fp32 (fused cast in staging),
// B bf16 via global_load_lds. 128x128 tile, BK=32, 4 waves.
// z<2 -> head-major Qh/Kh[bh][s][d]; z==2 -> Vtp[bh][d][s'] (permuted).
// grid (8, 32, 3), 256 threads.
// ---------------------------------------------------------------------------
__global__ __launch_bounds__(256)
void gemm_qkv(const float* __restrict__ qa, const float* __restrict__ ka,
              const float* __restrict__ va,
              const unsigned short* __restrict__ wq, const unsigned short* __restrict__ wk,
              const unsigned short* __restrict__ wv,
              const float* __restrict__ bq, const float* __restrict__ bk,
              const float* __restrict__ bv,
              unsigned short* __restrict__ Qh, unsigned short* __restrict__ Kh,
              unsigned short* __restrict__ Vtp)
{
    constexpr int K = 1024;
    __shared__ short As[128][40];            // padded (reg-staged)
    __shared__ unsigned short Bs[128 * 32];  // linear (global_load_lds)

    const int z = blockIdx.z;
    const float* A = (z == 0) ? qa : (z == 1) ? ka : va;
    const unsigned short* Bt = (z == 0) ? wq : (z == 1) ? wk : wv;
    const float* bias = (z == 0) ? bq : (z == 1) ? bk : bv;

    const int tid = threadIdx.x;
    const int bn = blockIdx.x, bm = blockIdx.y;
    const int wave = tid >> 6, lane = tid & 63;
    const int wr = wave >> 1, wc = wave & 1;
    const int lrow = lane & 15, g = lane >> 4;
    const int srow = tid >> 1, shalf = (tid & 1) * 16;
    const int gr = lane >> 2, gc = (lane & 3) * 8;   // gload pattern

    f32x4 acc[4][4] = {};

    for (int k0 = 0; k0 < K; k0 += 32) {
        // B tile via async global->LDS (wave w stages rows [w*32, w*32+32))
        gl16(Bt + (size_t)(bn * 128 + wave * 32 + gr) * K + k0 + gc,
             Bs + (wave * 32) * 32);
        gl16(Bt + (size_t)(bn * 128 + wave * 32 + 16 + gr) * K + k0 + gc,
             Bs + (wave * 32 + 16) * 32);
        // A tile: fp32 -> bf16 in regs
        {
            const float* ap = A + (size_t)(bm * 128 + srow) * K + k0 + shalf;
            float4 f0 = ((const float4*)ap)[0];
            float4 f1 = ((const float4*)ap)[1];
            float4 f2 = ((const float4*)ap)[2];
            float4 f3 = ((const float4*)ap)[3];
            uint4 lo = { pkbf(f0.x, f0.y), pkbf(f0.z, f0.w),
                         pkbf(f1.x, f1.y), pkbf(f1.z, f1.w) };
            uint4 hi = { pkbf(f2.x, f2.y), pkbf(f2.z, f2.w),
                         pkbf(f3.x, f3.y), pkbf(f3.z, f3.w) };
            *(uint4*)&As[srow][shalf] = lo;
            *(uint4*)&As[srow][shalf + 8] = hi;
        }
        __syncthreads();

        bf16x8 af[4], bfr[4];
#pragma unroll
        for (int i = 0; i < 4; ++i)
            af[i] = *(const bf16x8*)&As[wr * 64 + i * 16 + lrow][g * 8];
#pragma unroll
        for (int j = 0; j < 4; ++j)
            bfr[j] = *(const bf16x8*)&Bs[(wc * 64 + j * 16 + lrow) * 32 + g * 8];
#pragma unroll
        for (int i = 0; i < 4; ++i)
#pragma unroll
            for (int j = 0; j < 4; ++j)
                acc[i][j] = mfma16(af[i], bfr[j], acc[i][j]);
        __syncthreads();
    }

    // epilogue
#pragma unroll
    for (int j = 0; j < 4; ++j) {
        const int col = bn * 128 + wc * 64 + j * 16 + lrow;
        const float bb = bias[col];
        const int h = col >> 6, d = col & 63;
#pragma unroll
        for (int i = 0; i < 4; ++i) {
            const int row0 = bm * 128 + wr * 64 + i * 16 + 4 * g;
#pragma unroll
            for (int r = 0; r < 4; ++r) {
                const float v = acc[i][j][r] + bb;
                const unsigned short bfv = (unsigned short)(pkbf(v, v) & 0xffffu);
                const int row = row0 + r;
                const int s = row >> 1, b = row & 1;
                if (z != 2) {
                    unsigned short* C = (z == 0) ? Qh : Kh;
                    C[(size_t)(b * 16 + h) * HD + s * 64 + d] = bfv;
                } else {
                    // direct Vtp[bh][d][s'] with PV permutation baked
                    const int st = s >> 6, sl = s & 63;
                    const int kc = sl >> 5, r5 = sl & 31;
                    const int h2 = r5 >> 4, gg = (r5 >> 2) & 3, jj = r5 & 3;
                    const int sp = kc * 32 + gg * 8 + h2 * 4 + jj;
                    Vtp[(size_t)(b * 16 + h) * HD + (size_t)d * SEQ + st * 64 + sp] = bfv;
                }
            }
        }
    }
}

// ---------------------------------------------------------------------------
// attn_mfma: swapped-operand flash attention, no-max softmax, split-K,
// register-dieted: per-kt S (4 live regs), VALU l-accum (no ones-MFMA).
// Block = 32 q rows of one (b,h); wave w keys [512w, 512w+512).
// grid 2048 (XCD-swizzled), 256 threads, 4 waves/SIMD target.
// ---------------------------------------------------------------------------
__global__ __launch_bounds__(256, 4)
void attn_mfma(const unsigned short* __restrict__ Qh,
               const unsigned short* __restrict__ Kh,
               const unsigned short* __restrict__ Vtp,
               unsigned short* __restrict__ Xp)
{
    __shared__ float Om[4][32][65];   // per-wave partial O^T, padded
    __shared__ float Lp[4][32];       // per-wave partial l

    const int tid = threadIdx.x;
    const int fid = blockIdx.x;
    const int xcd = fid & 7, idx = fid >> 3;      // XCD swizzle
    const int bh = xcd * 4 + (idx >> 6);
    const int qt = idx & 63;

    const int wave = tid >> 6, lane = tid & 63;
    const int lrow = lane & 15, g = lane >> 4;
    const int q0 = qt * 32;
    const float CE = 0.18033688011112042592f;     // (1/sqrt(64)) * log2(e)

    const unsigned short* qb = Qh + (size_t)bh * HD;
    const unsigned short* kb = Kh + (size_t)bh * HD;
    const unsigned short* vb = Vtp + (size_t)bh * HD;

    bf16x8 bq[2][2];
#pragma unroll
    for (int qi = 0; qi < 2; ++qi)
#pragma unroll
        for (int dc = 0; dc < 2; ++dc)
            bq[qi][dc] = *(const bf16x8*)(qb + (size_t)(q0 + qi * 16 + lrow) * 64
                                             + dc * 32 + g * 8);

    f32x4 oacc[4][2] = {};
    float lsum0 = 0.f, lsum1 = 0.f;

    const int kbase = wave * 512;

#pragma unroll 1
    for (int t8 = 0; t8 < 8; ++t8) {
        const int kv0 = kbase + t8 * 64;

        bf16x8 ak[4][2];
#pragma unroll
        for (int kt = 0; kt < 4; ++kt)
#pragma unroll
            for (int dc = 0; dc < 2; ++dc)
                ak[kt][dc] = *(const bf16x8*)(kb + (size_t)(kv0 + kt * 16 + lrow) * 64
                                                 + dc * 32 + g * 8);
        bf16x8 av[4][2];
#pragma unroll
        for (int dt = 0; dt < 4; ++dt)
#pragma unroll
            for (int kc = 0; kc < 2; ++kc)
                av[dt][kc] = *(const bf16x8*)(vb + (size_t)(dt * 16 + lrow) * SEQ
                                                 + kv0 + kc * 32 + g * 8);

        // S per kt, exp+pack immediately (minimal live state)
        uint4 pbu[2][2];
#pragma unroll
        for (int qi = 0; qi < 2; ++qi) {
            float ll = 0.f;
#pragma unroll
            for (int kt = 0; kt < 4; ++kt) {
                f32x4 s = { 0.f, 0.f, 0.f, 0.f };
                s = mfma16(ak[kt][0], bq[qi][0], s);
                s = mfma16(ak[kt][1], bq[qi][1], s);
                const float p0 = __builtin_amdgcn_exp2f(s[0] * CE);
                const float p1 = __builtin_amdgcn_exp2f(s[1] * CE);
                const float p2 = __builtin_amdgcn_exp2f(s[2] * CE);
                const float p3 = __builtin_amdgcn_exp2f(s[3] * CE);
                ll += (p0 + p1) + (p2 + p3);
                const unsigned lo = pkbf(p0, p1);
                const unsigned hi = pkbf(p2, p3);
                if (kt & 1) { pbu[kt >> 1][qi].z = lo; pbu[kt >> 1][qi].w = hi; }
                else        { pbu[kt >> 1][qi].x = lo; pbu[kt >> 1][qi].y = hi; }
            }
            if (qi == 0) lsum0 += ll; else lsum1 += ll;
        }

        // O^T += V^T @ P^T
        __builtin_amdgcn_s_setprio(1);
#pragma unroll
        for (int kc = 0; kc < 2; ++kc)
#pragma unroll
            for (int dt = 0; dt < 4; ++dt)
#pragma unroll
                for (int qi = 0; qi < 2; ++qi) {
                    union { uint4 u; bf16x8 v; } cv;
                    cv.u = pbu[kc][qi];
                    oacc[dt][qi] = mfma16(av[dt][kc], cv.v, oacc[dt][qi]);
                }
        __builtin_amdgcn_s_setprio(0);
    }

    // reduce l across the 4 g-groups (lanes lrow, +16, +32, +48)
    float l0 = lsum0; l0 += __shfl_xor(l0, 16); l0 += __shfl_xor(l0, 32);
    float l1 = lsum1; l1 += __shfl_xor(l1, 16); l1 += __shfl_xor(l1, 32);

    // ---- merge epilogue: pure sum of per-wave partials (exact) ----
#pragma unroll
    for (int qi = 0; qi < 2; ++qi)
#pragma unroll
        for (int dt = 0; dt < 4; ++dt)
            *(f32x4*)&Om[wave][qi * 16 + lrow][dt * 16 + g * 4] = oacc[dt][qi];
    if (g == 0) {
        Lp[wave][lrow]      = l0;
        Lp[wave][16 + lrow] = l1;
    }
    __syncthreads();

    const int q  = tid >> 3;          // 0..31
    const int d0 = (tid & 7) * 8;     // 0..56
    const float lsum = Lp[0][q] + Lp[1][q] + Lp[2][q] + Lp[3][q];
    const float inv = 1.0f / lsum;
    float s[8];
#pragma unroll
    for (int j = 0; j < 8; ++j)
        s[j] = (Om[0][q][d0 + j] + Om[1][q][d0 + j] +
                Om[2][q][d0 + j] + Om[3][q][d0 + j]) * inv;
    uint4 u = { pkbf(s[0], s[1]), pkbf(s[2], s[3]),
                pkbf(s[4], s[5]), pkbf(s[6], s[7]) };
    *(uint4*)(Xp + (size_t)(q0 + q) * SST + bh * 64 + d0) = u;
}

// ---------------------------------------------------------------------------
// gemm_out: out[4096][1024] = Xp(bf16) @ WtO^T + bo, fp32 out.
// 128x64 tile, BK=32, both operands via global_load_lds. grid (16, 32).
// ---------------------------------------------------------------------------
__global__ __launch_bounds__(256)
void gemm_out(const unsigned short* __restrict__ Xp,
              const unsigned short* __restrict__ WtO,
              const float* __restrict__ bias, float* __restrict__ out)
{
    constexpr int K = 1024, N = 1024;
    __shared__ unsigned short As[128 * 32];
    __shared__ unsigned short Bs[64 * 32];

    const int tid = threadIdx.x;
    const int bn = blockIdx.x, bm = blockIdx.y;
    const int wave = tid >> 6, lane = tid & 63;
    const int wr = wave >> 1, wc = wave & 1;
    const int lrow = lane & 15, g = lane >> 4;
    const int gr = lane >> 2, gc = (lane & 3) * 8;

    f32x4 acc[4][2] = {};

    for (int k0 = 0; k0 < K; k0 += 32) {
        gl16(Xp + (size_t)(bm * 128 + wave * 32 + gr) * K + k0 + gc,
             As + (wave * 32) * 32);
        gl16(Xp + (size_t)(bm * 128 + wave * 32 + 16 + gr) * K + k0 + gc,
             As + (wave * 32 + 16) * 32);
        gl16(WtO + (size_t)(bn * 64 + wave * 16 + gr) * K + k0 + gc,
             Bs + (wave * 16) * 32);
        __syncthreads();

        bf16x8 af[4], bfr[2];
#pragma unroll
        for (int i = 0; i < 4; ++i)
            af[i] = *(const bf16x8*)&As[(wr * 64 + i * 16 + lrow) * 32 + g * 8];
#pragma unroll
        for (int j = 0; j < 2; ++j)
            bfr[j] = *(const bf16x8*)&Bs[(wc * 32 + j * 16 + lrow) * 32 + g * 8];
#pragma unroll
        for (int i = 0; i < 4; ++i)
#pragma unroll
            for (int j = 0; j < 2; ++j)
                acc[i][j] = mfma16(af[i], bfr[j], acc[i][j]);
        __syncthreads();
    }

#pragma unroll
    for (int j = 0; j < 2; ++j) {
        const int col = bn * 64 + wc * 32 + j * 16 + lrow;
        const float bb = bias[col];
#pragma unroll
        for (int i = 0; i < 4; ++i) {
            const int row0 = bm * 128 + wr * 64 + i * 16 + 4 * g;
#pragma unroll
            for (int r = 0; r < 4; ++r)
                out[(size_t)(row0 + r) * N + col] = acc[i][j][r] + bb;
        }
    }
}

// ---------------------------------------------------------------------------
// kernel_launch
// ws (shorts): WtQ 0 | WtK 1M | WtV 2M | WtO 3M | Qh 4M | Kh 8M | Vtp 12M |
//              Xp 16M    (20M shorts = 40 MB)
// ---------------------------------------------------------------------------
extern "C" void kernel_launch(void* const* d_in, const int* in_sizes, int n_in,
                              void* d_out, int out_size, void* d_ws, size_t ws_size,
                              hipStream_t stream) {
    (void)in_sizes; (void)n_in; (void)out_size; (void)ws_size;

    const float* q  = (const float*)d_in[0];
    const float* k  = (const float*)d_in[1];
    const float* v  = (const float*)d_in[2];
    const float* Wq = (const float*)d_in[3];
    const float* bq = (const float*)d_in[4];
    const float* Wk = (const float*)d_in[5];
    const float* bk = (const float*)d_in[6];
    const float* Wv = (const float*)d_in[7];
    const float* bv = (const float*)d_in[8];
    const float* Wo = (const float*)d_in[9];
    const float* bo = (const float*)d_in[10];
    float* out = (float*)d_out;

    unsigned short* ws = (unsigned short*)d_ws;
    const size_t WSZ = (size_t)DM * DM;      // 1M shorts
    const size_t MSZ = (size_t)MR * DM;      // 4M shorts
    unsigned short* WtQ = ws;
    unsigned short* WtK = ws + WSZ;
    unsigned short* WtV = ws + 2 * WSZ;
    unsigned short* WtO = ws + 3 * WSZ;
    unsigned short* Qh  = ws + 4 * WSZ;
    unsigned short* Kh  = Qh + MSZ;
    unsigned short* Vtp = Kh + MSZ;
    unsigned short* Xp  = Vtp + MSZ;

    const dim3 blk(256);

    wt_prep_all<<<dim3(16, 4, 4), blk, 0, stream>>>(Wq, Wk, Wv, Wo, WtQ, WtK, WtV, WtO);

    gemm_qkv<<<dim3(8, 32, 3), blk, 0, stream>>>(q, k, v, WtQ, WtK, WtV,
                                                 bq, bk, bv, Qh, Kh, Vtp);

    attn_mfma<<<dim3(2048), blk, 0, stream>>>(Qh, Kh, Vtp, Xp);

    gemm_out<<<dim3(16, 32), blk, 0, stream>>>(Xp, WtO, bo, out);
}

// Round 8
// 151.891 us; speedup vs baseline: 1.7928x; 1.7928x over previous
//
#include <hip/hip_runtime.h>
#include <hip/hip_bf16.h>

// ---------------------------------------------------------------------------
// MHA forward, bf16 MFMA.
//   wt_prep_all      : 4 W fp32 -> Wt bf16 transposed [e][d]
//   gemm_qkv (z=0..2): q/k/v @ Wt + b -> Qh/Kh head-major; z==2 writes
//                      Vtp[bh][d][s'] DIRECTLY (PV permutation baked)
//   attn_mfma        : flash attn, no-max softmax; K/V LDS-staged per block
//                      (async global_load_lds, dbuf, XOR-swizzle via source)
//   gemm_out         : Xp @ WtO + bo -> out fp32 (global_load_lds staging)
// ---------------------------------------------------------------------------

typedef __attribute__((ext_vector_type(8))) short bf16x8;   // 8 bf16 = 4 VGPR
typedef __attribute__((ext_vector_type(4))) float f32x4;    // MFMA acc

constexpr int SEQ   = 2048;
constexpr int BATCH = 2;
constexpr int DM    = 1024;
constexpr int DK    = 64;
constexpr int MR    = SEQ * BATCH;    // 4096 GEMM rows
constexpr int SST   = BATCH * DM;     // 2048 shorts per s-step in std layout
constexpr int HD    = SEQ * DK;       // 131072 shorts per (b,h) head-major

__device__ __forceinline__ unsigned pkbf(float a, float b) {
    __hip_bfloat162 h = __float22bfloat162_rn(float2{a, b});
    union { __hip_bfloat162 h2; unsigned u; } cv;
    cv.h2 = h;
    return cv.u;
}

__device__ __forceinline__ f32x4 mfma16(bf16x8 a, bf16x8 b, f32x4 c) {
    return __builtin_amdgcn_mfma_f32_16x16x32_bf16(a, b, c, 0, 0, 0);
}

// async global->LDS, 16B per lane; lds base must be wave-uniform
__device__ __forceinline__ void gl16(const unsigned short* g, unsigned short* l) {
    __builtin_amdgcn_global_load_lds(
        (const __attribute__((address_space(1))) void*)g,
        (__attribute__((address_space(3))) void*)l, 16, 0, 0);
}

// ---------------------------------------------------------------------------
// wt_prep_all: Wt[e][d] = bf16(W[d][e]) for all 4 weight matrices.
// grid (16, 4, 4), 256 threads.
// ---------------------------------------------------------------------------
__global__ __launch_bounds__(256)
void wt_prep_all(const float* __restrict__ w0, const float* __restrict__ w1,
                 const float* __restrict__ w2, const float* __restrict__ w3,
                 unsigned short* __restrict__ o0, unsigned short* __restrict__ o1,
                 unsigned short* __restrict__ o2, unsigned short* __restrict__ o3)
{
    const int z = blockIdx.z;
    const float* W = (z == 0) ? w0 : (z == 1) ? w1 : (z == 2) ? w2 : w3;
    unsigned short* Wt = (z == 0) ? o0 : (z == 1) ? o1 : (z == 2) ? o2 : o3;

    const int t = threadIdx.x;
    const int e = blockIdx.x * 64 + (t & 63);
    const int dq = blockIdx.y * 256 + (t >> 6) * 64;
    unsigned short* orow = Wt + (size_t)e * DM + dq;
#pragma unroll
    for (int c = 0; c < 8; ++c) {
        float f[8];
#pragma unroll
        for (int j = 0; j < 8; ++j)
            f[j] = W[(size_t)(dq + c * 8 + j) * DM + e];
        uint4 u = { pkbf(f[0], f[1]), pkbf(f[2], f[3]),
                    pkbf(f[4], f[5]), pkbf(f[6], f[7]) };
        *(uint4*)(orow + c * 8) = u;
    }
}

// ---------------------------------------------------------------------------
// gemm_qkv: C = A[4096][1024] @ Wt^T + bias. A fp32 (fused cast in staging),
// B bf16 via global_load_lds. 128x128 tile, BK=32, 4 waves.
// z<2 -> head-major Qh/Kh[bh][s][d]; z==2 -> Vtp[bh][d][s'] (permuted).
// grid (8, 32, 3), 256 threads.
// ---------------------------------------------------------------------------
__global__ __launch_bounds__(256)
void gemm_qkv(const float* __restrict__ qa, const float* __restrict__ ka,
              const float* __restrict__ va,
              const unsigned short* __restrict__ wq, const unsigned short* __restrict__ wk,
              const unsigned short* __restrict__ wv,
              const float* __restrict__ bq, const float* __restrict__ bk,
              const float* __restrict__ bv,
              unsigned short* __restrict__ Qh, unsigned short* __restrict__ Kh,
              unsigned short* __restrict__ Vtp)
{
    constexpr int K = 1024;
    __shared__ short As[128][40];            // padded (reg-staged)
    __shared__ unsigned short Bs[128 * 32];  // linear (global_load_lds)

    const int z = blockIdx.z;
    const float* A = (z == 0) ? qa : (z == 1) ? ka : va;
    const unsigned short* Bt = (z == 0) ? wq : (z == 1) ? wk : wv;
    const float* bias = (z == 0) ? bq : (z == 1) ? bk : bv;

    const int tid = threadIdx.x;
    const int bn = blockIdx.x, bm = blockIdx.y;
    const int wave = tid >> 6, lane = tid & 63;
    const int wr = wave >> 1, wc = wave & 1;
    const int lrow = lane & 15, g = lane >> 4;
    const int srow = tid >> 1, shalf = (tid & 1) * 16;
    const int gr = lane >> 2, gc = (lane & 3) * 8;   // gload pattern

    f32x4 acc[4][4] = {};

    for (int k0 = 0; k0 < K; k0 += 32) {
        // B tile via async global->LDS (wave w stages rows [w*32, w*32+32))
        gl16(Bt + (size_t)(bn * 128 + wave * 32 + gr) * K + k0 + gc,
             Bs + (wave * 32) * 32);
        gl16(Bt + (size_t)(bn * 128 + wave * 32 + 16 + gr) * K + k0 + gc,
             Bs + (wave * 32 + 16) * 32);
        // A tile: fp32 -> bf16 in regs
        {
            const float* ap = A + (size_t)(bm * 128 + srow) * K + k0 + shalf;
            float4 f0 = ((const float4*)ap)[0];
            float4 f1 = ((const float4*)ap)[1];
            float4 f2 = ((const float4*)ap)[2];
            float4 f3 = ((const float4*)ap)[3];
            uint4 lo = { pkbf(f0.x, f0.y), pkbf(f0.z, f0.w),
                         pkbf(f1.x, f1.y), pkbf(f1.z, f1.w) };
            uint4 hi = { pkbf(f2.x, f2.y), pkbf(f2.z, f2.w),
                         pkbf(f3.x, f3.y), pkbf(f3.z, f3.w) };
            *(uint4*)&As[srow][shalf] = lo;
            *(uint4*)&As[srow][shalf + 8] = hi;
        }
        __syncthreads();

        bf16x8 af[4], bfr[4];
#pragma unroll
        for (int i = 0; i < 4; ++i)
            af[i] = *(const bf16x8*)&As[wr * 64 + i * 16 + lrow][g * 8];
#pragma unroll
        for (int j = 0; j < 4; ++j)
            bfr[j] = *(const bf16x8*)&Bs[(wc * 64 + j * 16 + lrow) * 32 + g * 8];
#pragma unroll
        for (int i = 0; i < 4; ++i)
#pragma unroll
            for (int j = 0; j < 4; ++j)
                acc[i][j] = mfma16(af[i], bfr[j], acc[i][j]);
        __syncthreads();
    }

    // epilogue
#pragma unroll
    for (int j = 0; j < 4; ++j) {
        const int col = bn * 128 + wc * 64 + j * 16 + lrow;
        const float bb = bias[col];
        const int h = col >> 6, d = col & 63;
#pragma unroll
        for (int i = 0; i < 4; ++i) {
            const int row0 = bm * 128 + wr * 64 + i * 16 + 4 * g;
#pragma unroll
            for (int r = 0; r < 4; ++r) {
                const float v = acc[i][j][r] + bb;
                const unsigned short bfv = (unsigned short)(pkbf(v, v) & 0xffffu);
                const int row = row0 + r;
                const int s = row >> 1, b = row & 1;
                if (z != 2) {
                    unsigned short* C = (z == 0) ? Qh : Kh;
                    C[(size_t)(b * 16 + h) * HD + s * 64 + d] = bfv;
                } else {
                    // direct Vtp[bh][d][s'] with PV permutation baked
                    const int st = s >> 6, sl = s & 63;
                    const int kc = sl >> 5, r5 = sl & 31;
                    const int h2 = r5 >> 4, gg = (r5 >> 2) & 3, jj = r5 & 3;
                    const int sp = kc * 32 + gg * 8 + h2 * 4 + jj;
                    Vtp[(size_t)(b * 16 + h) * HD + (size_t)d * SEQ + st * 64 + sp] = bfv;
                }
            }
        }
    }
}

// ---------------------------------------------------------------------------
// attn_mfma: swapped-operand flash attention, no-max softmax.
// Block = 4 waves x 32 q rows (128 q) of one (b,h); iterate 32 64-key tiles.
// K/V tiles staged in LDS via async global_load_lds, double-buffered, shared
// by all 4 waves. XOR-swizzle (T2) applied by pre-swizzling the 16B-chunk
// index in the GLOBAL source address (LDS dest stays linear, m173) and
// un-swizzling on ds_read -> <=2-way bank conflicts.
// grid 512 (XCD-swizzled), 256 threads.
// ---------------------------------------------------------------------------
__global__ __launch_bounds__(256)
void attn_mfma(const unsigned short* __restrict__ Qh,
               const unsigned short* __restrict__ Kh,
               const unsigned short* __restrict__ Vtp,
               unsigned short* __restrict__ Xp)
{
    __shared__ unsigned short lds[16384];   // K0 | V0 | K1 | V1, 4096 shorts each

    const int tid = threadIdx.x;
    const int fid = blockIdx.x;
    const int xcd = fid & 7, idx = fid >> 3;      // XCD swizzle: xcd owns 4 bh
    const int bh = xcd * 4 + (idx >> 4);
    const int qt = idx & 15;

    const int wave = tid >> 6, lane = tid & 63;
    const int lrow = lane & 15, g = lane >> 4;
    const int s7 = lrow & 7;
    const int q0w = qt * 128 + wave * 32;
    const float CE = 0.18033688011112042592f;     // (1/sqrt(64)) * log2(e)

    const unsigned short* qb = Qh + (size_t)bh * HD;
    const unsigned short* kb = Kh + (size_t)bh * HD;
    const unsigned short* vb = Vtp + (size_t)bh * HD;

    unsigned short* K0 = lds;
    unsigned short* V0 = lds + 4096;
    unsigned short* K1 = lds + 8192;
    unsigned short* V1 = lds + 12288;

    // staging source (pre-swizzled chunk index: chunk ^ (row&7))
    const int r8 = lane >> 3, c8 = lane & 7;
    const unsigned short* ksrcA = kb + (size_t)(wave * 16 + r8) * 64 + (c8 ^ r8) * 8;
    const unsigned short* ksrcB = ksrcA + 8 * 64;
    const unsigned short* vsrcA = vb + (size_t)(wave * 16 + r8) * SEQ + (c8 ^ r8) * 8;
    const unsigned short* vsrcB = vsrcA + 8 * SEQ;

    auto stage = [&](unsigned short* kbuf, unsigned short* vbuf, int t) {
        const size_t ko = (size_t)t * 4096;   // 64 rows * 64 shorts per tile
        const size_t vo = (size_t)t * 64;     // 64 cols per tile
        gl16(ksrcA + ko, kbuf + wave * 1024);
        gl16(ksrcB + ko, kbuf + wave * 1024 + 512);
        gl16(vsrcA + vo, vbuf + wave * 1024);
        gl16(vsrcB + vo, vbuf + wave * 1024 + 512);
    };

    // Q^T fragments (loaded once)
    bf16x8 bq[2][2];
#pragma unroll
    for (int qi = 0; qi < 2; ++qi)
#pragma unroll
        for (int dc = 0; dc < 2; ++dc)
            bq[qi][dc] = *(const bf16x8*)(qb + (size_t)(q0w + qi * 16 + lrow) * 64
                                             + dc * 32 + g * 8);

    f32x4 oacc[4][2] = {};
    float lsum0 = 0.f, lsum1 = 0.f;

    // un-swizzled read offsets (shorts): row lrow, chunk (c*4+g) ^ s7
    const int off0 = lrow * 64 + ((g ^ s7) * 8);
    const int off1 = lrow * 64 + (((4 + g) ^ s7) * 8);

    auto compute = [&](const unsigned short* kbuf, const unsigned short* vbuf) {
        bf16x8 ak[4][2];
#pragma unroll
        for (int kt = 0; kt < 4; ++kt) {
            ak[kt][0] = *(const bf16x8*)(kbuf + kt * 1024 + off0);
            ak[kt][1] = *(const bf16x8*)(kbuf + kt * 1024 + off1);
        }

        // S per kt, exp+pack immediately
        uint4 pbu[2][2];
#pragma unroll
        for (int qi = 0; qi < 2; ++qi) {
            float ll = 0.f;
#pragma unroll
            for (int kt = 0; kt < 4; ++kt) {
                f32x4 s = { 0.f, 0.f, 0.f, 0.f };
                s = mfma16(ak[kt][0], bq[qi][0], s);
                s = mfma16(ak[kt][1], bq[qi][1], s);
                const float p0 = __builtin_amdgcn_exp2f(s[0] * CE);
                const float p1 = __builtin_amdgcn_exp2f(s[1] * CE);
                const float p2 = __builtin_amdgcn_exp2f(s[2] * CE);
                const float p3 = __builtin_amdgcn_exp2f(s[3] * CE);
                ll += (p0 + p1) + (p2 + p3);
                const unsigned lo = pkbf(p0, p1);
                const unsigned hi = pkbf(p2, p3);
                if (kt & 1) { pbu[kt >> 1][qi].z = lo; pbu[kt >> 1][qi].w = hi; }
                else        { pbu[kt >> 1][qi].x = lo; pbu[kt >> 1][qi].y = hi; }
            }
            if (qi == 0) lsum0 += ll; else lsum1 += ll;
        }

        bf16x8 av[4][2];
#pragma unroll
        for (int dt = 0; dt < 4; ++dt) {
            av[dt][0] = *(const bf16x8*)(vbuf + dt * 1024 + off0);
            av[dt][1] = *(const bf16x8*)(vbuf + dt * 1024 + off1);
        }

        __builtin_amdgcn_s_setprio(1);
#pragma unroll
        for (int kc = 0; kc < 2; ++kc)
#pragma unroll
            for (int dt = 0; dt < 4; ++dt)
#pragma unroll
                for (int qi = 0; qi < 2; ++qi) {
                    union { uint4 u; bf16x8 v; } cv;
                    cv.u = pbu[kc][qi];
                    oacc[dt][qi] = mfma16(av[dt][kc], cv.v, oacc[dt][qi]);
                }
        __builtin_amdgcn_s_setprio(0);
    };

    // prologue: stage tile 0, wait, barrier
    stage(K0, V0, 0);
    asm volatile("s_waitcnt vmcnt(0)" ::: "memory");
    __syncthreads();

#pragma unroll 1
    for (int tt = 0; tt < 16; ++tt) {
        stage(K1, V1, 2 * tt + 1);      // async, lands before next barrier
        compute(K0, V0);
        __syncthreads();
        if (tt < 15) stage(K0, V0, 2 * tt + 2);
        compute(K1, V1);
        __syncthreads();
    }

    // l reduce across the 4 g-groups
    float l0 = lsum0; l0 += __shfl_xor(l0, 16); l0 += __shfl_xor(l0, 32);
    float l1 = lsum1; l1 += __shfl_xor(l1, 16); l1 += __shfl_xor(l1, 32);
    const float inv0 = 1.0f / l0, inv1 = 1.0f / l1;

    // epilogue: normalize, transpose via reused LDS (wave-private), store
    unsigned short (*osh)[72] = (unsigned short (*)[72])(lds + wave * 32 * 72);
#pragma unroll
    for (int qi = 0; qi < 2; ++qi) {
        const float inv = qi ? inv1 : inv0;
#pragma unroll
        for (int dt = 0; dt < 4; ++dt) {
            const int d0 = dt * 16 + 4 * g;
            const unsigned u0 = pkbf(oacc[dt][qi][0] * inv, oacc[dt][qi][1] * inv);
            const unsigned u1 = pkbf(oacc[dt][qi][2] * inv, oacc[dt][qi][3] * inv);
            *(unsigned*)&osh[qi * 16 + lrow][d0] = u0;
            *(unsigned*)&osh[qi * 16 + lrow][d0 + 2] = u1;
        }
    }
    const int ql = lane >> 1;
    const int dh = (lane & 1) * 32;
    unsigned short* xrow = Xp + (size_t)(q0w + ql) * SST + bh * 64 + dh;
#pragma unroll
    for (int c = 0; c < 4; ++c) {
        uint4 vv = *(const uint4*)&osh[ql][dh + c * 8];
        *(uint4*)(xrow + c * 8) = vv;
    }
}

// ---------------------------------------------------------------------------
// gemm_out: out[4096][1024] = Xp(bf16) @ WtO^T + bo, fp32 out.
// 128x64 tile, BK=32, both operands via global_load_lds. grid (16, 32).
// ---------------------------------------------------------------------------
__global__ __launch_bounds__(256)
void gemm_out(const unsigned short* __restrict__ Xp,
              const unsigned short* __restrict__ WtO,
              const float* __restrict__ bias, float* __restrict__ out)
{
    constexpr int K = 1024, N = 1024;
    __shared__ unsigned short As[128 * 32];
    __shared__ unsigned short Bs[64 * 32];

    const int tid = threadIdx.x;
    const int bn = blockIdx.x, bm = blockIdx.y;
    const int wave = tid >> 6, lane = tid & 63;
    const int wr = wave >> 1, wc = wave & 1;
    const int lrow = lane & 15, g = lane >> 4;
    const int gr = lane >> 2, gc = (lane & 3) * 8;

    f32x4 acc[4][2] = {};

    for (int k0 = 0; k0 < K; k0 += 32) {
        gl16(Xp + (size_t)(bm * 128 + wave * 32 + gr) * K + k0 + gc,
             As + (wave * 32) * 32);
        gl16(Xp + (size_t)(bm * 128 + wave * 32 + 16 + gr) * K + k0 + gc,
             As + (wave * 32 + 16) * 32);
        gl16(WtO + (size_t)(bn * 64 + wave * 16 + gr) * K + k0 + gc,
             Bs + (wave * 16) * 32);
        __syncthreads();

        bf16x8 af[4], bfr[2];
#pragma unroll
        for (int i = 0; i < 4; ++i)
            af[i] = *(const bf16x8*)&As[(wr * 64 + i * 16 + lrow) * 32 + g * 8];
#pragma unroll
        for (int j = 0; j < 2; ++j)
            bfr[j] = *(const bf16x8*)&Bs[(wc * 32 + j * 16 + lrow) * 32 + g * 8];
#pragma unroll
        for (int i = 0; i < 4; ++i)
#pragma unroll
            for (int j = 0; j < 2; ++j)
                acc[i][j] = mfma16(af[i], bfr[j], acc[i][j]);
        __syncthreads();
    }

#pragma unroll
    for (int j = 0; j < 2; ++j) {
        const int col = bn * 64 + wc * 32 + j * 16 + lrow;
        const float bb = bias[col];
#pragma unroll
        for (int i = 0; i < 4; ++i) {
            const int row0 = bm * 128 + wr * 64 + i * 16 + 4 * g;
#pragma unroll
            for (int r = 0; r < 4; ++r)
                out[(size_t)(row0 + r) * N + col] = acc[i][j][r] + bb;
        }
    }
}

// ---------------------------------------------------------------------------
// kernel_launch
// ws (shorts): WtQ 0 | WtK 1M | WtV 2M | WtO 3M | Qh 4M | Kh 8M | Vtp 12M |
//              Xp 16M    (20M shorts = 40 MB)
// ---------------------------------------------------------------------------
extern "C" void kernel_launch(void* const* d_in, const int* in_sizes, int n_in,
                              void* d_out, int out_size, void* d_ws, size_t ws_size,
                              hipStream_t stream) {
    (void)in_sizes; (void)n_in; (void)out_size; (void)ws_size;

    const float* q  = (const float*)d_in[0];
    const float* k  = (const float*)d_in[1];
    const float* v  = (const float*)d_in[2];
    const float* Wq = (const float*)d_in[3];
    const float* bq = (const float*)d_in[4];
    const float* Wk = (const float*)d_in[5];
    const float* bk = (const float*)d_in[6];
    const float* Wv = (const float*)d_in[7];
    const float* bv = (const float*)d_in[8];
    const float* Wo = (const float*)d_in[9];
    const float* bo = (const float*)d_in[10];
    float* out = (float*)d_out;

    unsigned short* ws = (unsigned short*)d_ws;
    const size_t WSZ = (size_t)DM * DM;      // 1M shorts
    const size_t MSZ = (size_t)MR * DM;      // 4M shorts
    unsigned short* WtQ = ws;
    unsigned short* WtK = ws + WSZ;
    unsigned short* WtV = ws + 2 * WSZ;
    unsigned short* WtO = ws + 3 * WSZ;
    unsigned short* Qh  = ws + 4 * WSZ;
    unsigned short* Kh  = Qh + MSZ;
    unsigned short* Vtp = Kh + MSZ;
    unsigned short* Xp  = Vtp + MSZ;

    const dim3 blk(256);

    wt_prep_all<<<dim3(16, 4, 4), blk, 0, stream>>>(Wq, Wk, Wv, Wo, WtQ, WtK, WtV, WtO);

    gemm_qkv<<<dim3(8, 32, 3), blk, 0, stream>>>(q, k, v, WtQ, WtK, WtV,
                                                 bq, bk, bv, Qh, Kh, Vtp);

    attn_mfma<<<dim3(512), blk, 0, stream>>>(Qh, Kh, Vtp, Xp);

    gemm_out<<<dim3(16, 32), blk, 0, stream>>>(Xp, WtO, bo, out);
}

// Round 10
// 145.553 us; speedup vs baseline: 1.8708x; 1.0435x over previous
//
#include <hip/hip_runtime.h>
#include <hip/hip_bf16.h>

// ---------------------------------------------------------------------------
// MHA forward, bf16 MFMA.
//   wt_prep_all      : 4 W fp32 -> Wt bf16 transposed [e][d]
//   gemm_qkv (z=0..2): q/k/v @ Wt + b -> Qh/Kh head-major; z==2 writes
//                      Vtp[bh][d][s'] DIRECTLY (PV permutation baked).
//                      XCD bm-ownership swizzle + conflict-free B staging
//                      (transposed-linear groups of 512 shorts).
//   attn_mfma        : flash attn, no-max softmax; K/V LDS-staged, dbuf
//   gemm_out         : Xp @ WtO + bo -> out fp32; same swizzle + staging
// ---------------------------------------------------------------------------

typedef __attribute__((ext_vector_type(8))) short bf16x8;   // 8 bf16 = 4 VGPR
typedef __attribute__((ext_vector_type(4))) float f32x4;    // MFMA acc

constexpr int SEQ   = 2048;
constexpr int BATCH = 2;
constexpr int DM    = 1024;
constexpr int DK    = 64;
constexpr int MR    = SEQ * BATCH;    // 4096 GEMM rows
constexpr int SST   = BATCH * DM;     // 2048 shorts per s-step in std layout
constexpr int HD    = SEQ * DK;       // 131072 shorts per (b,h) head-major

__device__ __forceinline__ unsigned pkbf(float a, float b) {
    __hip_bfloat162 h = __float22bfloat162_rn(float2{a, b});
    union { __hip_bfloat162 h2; unsigned u; } cv;
    cv.h2 = h;
    return cv.u;
}

__device__ __forceinline__ f32x4 mfma16(bf16x8 a, bf16x8 b, f32x4 c) {
    return __builtin_amdgcn_mfma_f32_16x16x32_bf16(a, b, c, 0, 0, 0);
}

// async global->LDS, 16B per lane; lds base must be wave-uniform
__device__ __forceinline__ void gl16(const unsigned short* g, unsigned short* l) {
    __builtin_amdgcn_global_load_lds(
        (const __attribute__((address_space(1))) void*)g,
        (__attribute__((address_space(3))) void*)l, 16, 0, 0);
}

// ---------------------------------------------------------------------------
// wt_prep_all: Wt[e][d] = bf16(W[d][e]) for all 4 weight matrices.
// grid (16, 4, 4), 256 threads.
// ---------------------------------------------------------------------------
__global__ __launch_bounds__(256)
void wt_prep_all(const float* __restrict__ w0, const float* __restrict__ w1,
                 const float* __restrict__ w2, const float* __restrict__ w3,
                 unsigned short* __restrict__ o0, unsigned short* __restrict__ o1,
                 unsigned short* __restrict__ o2, unsigned short* __restrict__ o3)
{
    const int z = blockIdx.z;
    const float* W = (z == 0) ? w0 : (z == 1) ? w1 : (z == 2) ? w2 : w3;
    unsigned short* Wt = (z == 0) ? o0 : (z == 1) ? o1 : (z == 2) ? o2 : o3;

    const int t = threadIdx.x;
    const int e = blockIdx.x * 64 + (t & 63);
    const int dq = blockIdx.y * 256 + (t >> 6) * 64;
    unsigned short* orow = Wt + (size_t)e * DM + dq;
#pragma unroll
    for (int c = 0; c < 8; ++c) {
        float f[8];
#pragma unroll
        for (int j = 0; j < 8; ++j)
            f[j] = W[(size_t)(dq + c * 8 + j) * DM + e];
        uint4 u = { pkbf(f[0], f[1]), pkbf(f[2], f[3]),
                    pkbf(f[4], f[5]), pkbf(f[6], f[7]) };
        *(uint4*)(orow + c * 8) = u;
    }
}

// ---------------------------------------------------------------------------
// gemm_qkv: C = A[4096][1024] @ Wt^T + bias. A fp32 (fused cast, reg-staged,
// padded LDS); B bf16 via global_load_lds in transposed-linear layout:
// lane l stages row (l&15), chunk (l>>4) -> group of 512 shorts, fragment
// read = grp*512 + lane*8 (16B/lane linear, zero bank conflicts).
// XCD swizzle: XCD x owns bm in [4x,4x+4) x all bn.
// grid (8, 32, 3), 256 threads.
// ---------------------------------------------------------------------------
__global__ __launch_bounds__(256)
void gemm_qkv(const float* __restrict__ qa, const float* __restrict__ ka,
              const float* __restrict__ va,
              const unsigned short* __restrict__ wq, const unsigned short* __restrict__ wk,
              const unsigned short* __restrict__ wv,
              const float* __restrict__ bq, const float* __restrict__ bk,
              const float* __restrict__ bv,
              unsigned short* __restrict__ Qh, unsigned short* __restrict__ Kh,
              unsigned short* __restrict__ Vtp)
{
    constexpr int K = 1024;
    __shared__ short As[128][40];            // padded (reg-staged, <=2-way)
    __shared__ unsigned short Bs[128 * 32];  // transposed-linear (gl16)

    const int z = blockIdx.z;
    const float* A = (z == 0) ? qa : (z == 1) ? ka : va;
    const unsigned short* Bt = (z == 0) ? wq : (z == 1) ? wk : wv;
    const float* bias = (z == 0) ? bq : (z == 1) ? bk : bv;

    // XCD bm-ownership swizzle: linear l -> xcd = l%8 owns bm 4*xcd..4*xcd+3
    const int l = blockIdx.x + 8 * blockIdx.y;   // 0..255
    const int xcd = l & 7, jj0 = l >> 3;         // jj0 0..31
    const int bm = xcd * 4 + (jj0 >> 3);
    const int bn = jj0 & 7;

    const int tid = threadIdx.x;
    const int wave = tid >> 6, lane = tid & 63;
    const int wr = wave >> 1, wc = wave & 1;
    const int lrow = lane & 15, g = lane >> 4;
    const int srow = tid >> 1, shalf = (tid & 1) * 16;
    // staging source mapping for transposed-linear layout:
    const int gr = lane & 15, gc = (lane >> 4) * 8;

    f32x4 acc[4][4] = {};

    for (int k0 = 0; k0 < K; k0 += 32) {
        // B tile: wave w stages rows [w*32, w*32+32) as groups 2w, 2w+1
        gl16(Bt + (size_t)(bn * 128 + wave * 32 + gr) * K + k0 + gc,
             Bs + (2 * wave) * 512);
        gl16(Bt + (size_t)(bn * 128 + wave * 32 + 16 + gr) * K + k0 + gc,
             Bs + (2 * wave + 1) * 512);
        // A tile: fp32 -> bf16 in regs
        {
            const float* ap = A + (size_t)(bm * 128 + srow) * K + k0 + shalf;
            float4 f0 = ((const float4*)ap)[0];
            float4 f1 = ((const float4*)ap)[1];
            float4 f2 = ((const float4*)ap)[2];
            float4 f3 = ((const float4*)ap)[3];
            uint4 lo = { pkbf(f0.x, f0.y), pkbf(f0.z, f0.w),
                         pkbf(f1.x, f1.y), pkbf(f1.z, f1.w) };
            uint4 hi = { pkbf(f2.x, f2.y), pkbf(f2.z, f2.w),
                         pkbf(f3.x, f3.y), pkbf(f3.z, f3.w) };
            *(uint4*)&As[srow][shalf] = lo;
            *(uint4*)&As[srow][shalf + 8] = hi;
        }
        __syncthreads();

        bf16x8 af[4], bfr[4];
#pragma unroll
        for (int i = 0; i < 4; ++i)
            af[i] = *(const bf16x8*)&As[wr * 64 + i * 16 + lrow][g * 8];
#pragma unroll
        for (int j = 0; j < 4; ++j)   // row wc*64+j*16+lrow, chunk g -> linear
            bfr[j] = *(const bf16x8*)&Bs[(wc * 4 + j) * 512 + lane * 8];
#pragma unroll
        for (int i = 0; i < 4; ++i)
#pragma unroll
            for (int j = 0; j < 4; ++j)
                acc[i][j] = mfma16(af[i], bfr[j], acc[i][j]);
        __syncthreads();
    }

    // epilogue
#pragma unroll
    for (int j = 0; j < 4; ++j) {
        const int col = bn * 128 + wc * 64 + j * 16 + lrow;
        const float bb = bias[col];
        const int h = col >> 6, d = col & 63;
#pragma unroll
        for (int i = 0; i < 4; ++i) {
            const int row0 = bm * 128 + wr * 64 + i * 16 + 4 * g;
#pragma unroll
            for (int r = 0; r < 4; ++r) {
                const float v = acc[i][j][r] + bb;
                const unsigned short bfv = (unsigned short)(pkbf(v, v) & 0xffffu);
                const int row = row0 + r;
                const int s = row >> 1, b = row & 1;
                if (z != 2) {
                    unsigned short* C = (z == 0) ? Qh : Kh;
                    C[(size_t)(b * 16 + h) * HD + s * 64 + d] = bfv;
                } else {
                    // direct Vtp[bh][d][s'] with PV permutation baked
                    const int st = s >> 6, sl = s & 63;
                    const int kc = sl >> 5, r5 = sl & 31;
                    const int h2 = r5 >> 4, gg = (r5 >> 2) & 3, jv = r5 & 3;
                    const int sp = kc * 32 + gg * 8 + h2 * 4 + jv;
                    Vtp[(size_t)(b * 16 + h) * HD + (size_t)d * SEQ + st * 64 + sp] = bfv;
                }
            }
        }
    }
}

// ---------------------------------------------------------------------------
// attn_mfma: swapped-operand flash attention, no-max softmax.
// Block = 4 waves x 32 q rows (128 q) of one (b,h); 32 64-key tiles.
// K/V staged in LDS (async global_load_lds, dbuf, source-swizzled).
// grid 512 (XCD-swizzled), 256 threads.
// ---------------------------------------------------------------------------
__global__ __launch_bounds__(256)
void attn_mfma(const unsigned short* __restrict__ Qh,
               const unsigned short* __restrict__ Kh,
               const unsigned short* __restrict__ Vtp,
               unsigned short* __restrict__ Xp)
{
    __shared__ unsigned short lds[16384];   // K0 | V0 | K1 | V1

    const int tid = threadIdx.x;
    const int fid = blockIdx.x;
    const int xcd = fid & 7, idx = fid >> 3;      // XCD swizzle: xcd owns 4 bh
    const int bh = xcd * 4 + (idx >> 4);
    const int qt = idx & 15;

    const int wave = tid >> 6, lane = tid & 63;
    const int lrow = lane & 15, g = lane >> 4;
    const int s7 = lrow & 7;
    const int q0w = qt * 128 + wave * 32;
    const float CE = 0.18033688011112042592f;     // (1/sqrt(64)) * log2(e)

    const unsigned short* qb = Qh + (size_t)bh * HD;
    const unsigned short* kb = Kh + (size_t)bh * HD;
    const unsigned short* vb = Vtp + (size_t)bh * HD;

    unsigned short* K0 = lds;
    unsigned short* V0 = lds + 4096;
    unsigned short* K1 = lds + 8192;
    unsigned short* V1 = lds + 12288;

    // staging source (pre-swizzled chunk index: chunk ^ (row&7))
    const int r8 = lane >> 3, c8 = lane & 7;
    const unsigned short* ksrcA = kb + (size_t)(wave * 16 + r8) * 64 + (c8 ^ r8) * 8;
    const unsigned short* ksrcB = ksrcA + 8 * 64;
    const unsigned short* vsrcA = vb + (size_t)(wave * 16 + r8) * SEQ + (c8 ^ r8) * 8;
    const unsigned short* vsrcB = vsrcA + 8 * SEQ;

    auto stage = [&](unsigned short* kbuf, unsigned short* vbuf, int t) {
        const size_t ko = (size_t)t * 4096;   // 64 rows * 64 shorts per tile
        const size_t vo = (size_t)t * 64;     // 64 cols per tile
        gl16(ksrcA + ko, kbuf + wave * 1024);
        gl16(ksrcB + ko, kbuf + wave * 1024 + 512);
        gl16(vsrcA + vo, vbuf + wave * 1024);
        gl16(vsrcB + vo, vbuf + wave * 1024 + 512);
    };

    // Q^T fragments (loaded once)
    bf16x8 bq[2][2];
#pragma unroll
    for (int qi = 0; qi < 2; ++qi)
#pragma unroll
        for (int dc = 0; dc < 2; ++dc)
            bq[qi][dc] = *(const bf16x8*)(qb + (size_t)(q0w + qi * 16 + lrow) * 64
                                             + dc * 32 + g * 8);

    f32x4 oacc[4][2] = {};
    float lsum0 = 0.f, lsum1 = 0.f;

    // un-swizzled read offsets (shorts): row lrow, chunk (c*4+g) ^ s7
    const int off0 = lrow * 64 + ((g ^ s7) * 8);
    const int off1 = lrow * 64 + (((4 + g) ^ s7) * 8);

    auto compute = [&](const unsigned short* kbuf, const unsigned short* vbuf) {
        bf16x8 ak[4][2];
#pragma unroll
        for (int kt = 0; kt < 4; ++kt) {
            ak[kt][0] = *(const bf16x8*)(kbuf + kt * 1024 + off0);
            ak[kt][1] = *(const bf16x8*)(kbuf + kt * 1024 + off1);
        }

        // S per kt, exp+pack immediately
        uint4 pbu[2][2];
#pragma unroll
        for (int qi = 0; qi < 2; ++qi) {
            float ll = 0.f;
#pragma unroll
            for (int kt = 0; kt < 4; ++kt) {
                f32x4 s = { 0.f, 0.f, 0.f, 0.f };
                s = mfma16(ak[kt][0], bq[qi][0], s);
                s = mfma16(ak[kt][1], bq[qi][1], s);
                const float p0 = __builtin_amdgcn_exp2f(s[0] * CE);
                const float p1 = __builtin_amdgcn_exp2f(s[1] * CE);
                const float p2 = __builtin_amdgcn_exp2f(s[2] * CE);
                const float p3 = __builtin_amdgcn_exp2f(s[3] * CE);
                ll += (p0 + p1) + (p2 + p3);
                const unsigned lo = pkbf(p0, p1);
                const unsigned hi = pkbf(p2, p3);
                if (kt & 1) { pbu[kt >> 1][qi].z = lo; pbu[kt >> 1][qi].w = hi; }
                else        { pbu[kt >> 1][qi].x = lo; pbu[kt >> 1][qi].y = hi; }
            }
            if (qi == 0) lsum0 += ll; else lsum1 += ll;
        }

        bf16x8 av[4][2];
#pragma unroll
        for (int dt = 0; dt < 4; ++dt) {
            av[dt][0] = *(const bf16x8*)(vbuf + dt * 1024 + off0);
            av[dt][1] = *(const bf16x8*)(vbuf + dt * 1024 + off1);
        }

        __builtin_amdgcn_s_setprio(1);
#pragma unroll
        for (int kc = 0; kc < 2; ++kc)
#pragma unroll
            for (int dt = 0; dt < 4; ++dt)
#pragma unroll
                for (int qi = 0; qi < 2; ++qi) {
                    union { uint4 u; bf16x8 v; } cv;
                    cv.u = pbu[kc][qi];
                    oacc[dt][qi] = mfma16(av[dt][kc], cv.v, oacc[dt][qi]);
                }
        __builtin_amdgcn_s_setprio(0);
    };

    // prologue: stage tile 0, wait, barrier
    stage(K0, V0, 0);
    asm volatile("s_waitcnt vmcnt(0)" ::: "memory");
    __syncthreads();

#pragma unroll 1
    for (int tt = 0; tt < 16; ++tt) {
        stage(K1, V1, 2 * tt + 1);      // async; __syncthreads drains vmcnt
        compute(K0, V0);
        __syncthreads();
        if (tt < 15) stage(K0, V0, 2 * tt + 2);
        compute(K1, V1);
        __syncthreads();
    }

    // l reduce across the 4 g-groups
    float l0 = lsum0; l0 += __shfl_xor(l0, 16); l0 += __shfl_xor(l0, 32);
    float l1 = lsum1; l1 += __shfl_xor(l1, 16); l1 += __shfl_xor(l1, 32);
    const float inv0 = 1.0f / l0, inv1 = 1.0f / l1;

    // epilogue: normalize, transpose via reused LDS (wave-private), store
    unsigned short (*osh)[72] = (unsigned short (*)[72])(lds + wave * 32 * 72);
#pragma unroll
    for (int qi = 0; qi < 2; ++qi) {
        const float inv = qi ? inv1 : inv0;
#pragma unroll
        for (int dt = 0; dt < 4; ++dt) {
            const int d0 = dt * 16 + 4 * g;
            const unsigned u0 = pkbf(oacc[dt][qi][0] * inv, oacc[dt][qi][1] * inv);
            const unsigned u1 = pkbf(oacc[dt][qi][2] * inv, oacc[dt][qi][3] * inv);
            *(unsigned*)&osh[qi * 16 + lrow][d0] = u0;
            *(unsigned*)&osh[qi * 16 + lrow][d0 + 2] = u1;
        }
    }
    const int ql = lane >> 1;
    const int dh = (lane & 1) * 32;
    unsigned short* xrow = Xp + (size_t)(q0w + ql) * SST + bh * 64 + dh;
#pragma unroll
    for (int c = 0; c < 4; ++c) {
        uint4 vv = *(const uint4*)&osh[ql][dh + c * 8];
        *(uint4*)(xrow + c * 8) = vv;
    }
}

// ---------------------------------------------------------------------------
// gemm_out: out[4096][1024] = Xp(bf16) @ WtO^T + bo, fp32 out.
// 128x64 tile, BK=32, both operands via global_load_lds in transposed-linear
// layout (512-short groups, zero bank conflicts). XCD swizzle.
// grid (16, 32), 256 threads.
// ---------------------------------------------------------------------------
__global__ __launch_bounds__(256)
void gemm_out(const unsigned short* __restrict__ Xp,
              const unsigned short* __restrict__ WtO,
              const float* __restrict__ bias, float* __restrict__ out)
{
    constexpr int K = 1024, N = 1024;
    __shared__ unsigned short As[128 * 32];
    __shared__ unsigned short Bs[64 * 32];

    const int l = blockIdx.x + 16 * blockIdx.y;   // 0..511
    const int xcd = l & 7, jj0 = l >> 3;          // jj0 0..63
    const int bm = xcd * 4 + (jj0 >> 4);
    const int bn = jj0 & 15;

    const int tid = threadIdx.x;
    const int wave = tid >> 6, lane = tid & 63;
    const int wr = wave >> 1, wc = wave & 1;
    const int lrow = lane & 15, g = lane >> 4;
    const int gr = lane & 15, gc = (lane >> 4) * 8;

    f32x4 acc[4][2] = {};

    for (int k0 = 0; k0 < K; k0 += 32) {
        gl16(Xp + (size_t)(bm * 128 + wave * 32 + gr) * K + k0 + gc,
             As + (2 * wave) * 512);
        gl16(Xp + (size_t)(bm * 128 + wave * 32 + 16 + gr) * K + k0 + gc,
             As + (2 * wave + 1) * 512);
        gl16(WtO + (size_t)(bn * 64 + wave * 16 + gr) * K + k0 + gc,
             Bs + wave * 512);
        __syncthreads();

        bf16x8 af[4], bfr[2];
#pragma unroll
        for (int i = 0; i < 4; ++i)   // row wr*64+i*16+lrow, chunk g
            af[i] = *(const bf16x8*)&As[(wr * 4 + i) * 512 + lane * 8];
#pragma unroll
        for (int j = 0; j < 2; ++j)   // row wc*32+j*16+lrow, chunk g
            bfr[j] = *(const bf16x8*)&Bs[(wc * 2 + j) * 512 + lane * 8];
#pragma unroll
        for (int i = 0; i < 4; ++i)
#pragma unroll
            for (int j = 0; j < 2; ++j)
                acc[i][j] = mfma16(af[i], bfr[j], acc[i][j]);
        __syncthreads();
    }

#pragma unroll
    for (int j = 0; j < 2; ++j) {
        const int col = bn * 64 + wc * 32 + j * 16 + lrow;
        const float bb = bias[col];
#pragma unroll
        for (int i = 0; i < 4; ++i) {
            const int row0 = bm * 128 + wr * 64 + i * 16 + 4 * g;
#pragma unroll
            for (int r = 0; r < 4; ++r)
                out[(size_t)(row0 + r) * N + col] = acc[i][j][r] + bb;
        }
    }
}

// ---------------------------------------------------------------------------
// kernel_launch
// ws (shorts): WtQ 0 | WtK 1M | WtV 2M | WtO 3M | Qh 4M | Kh 8M | Vtp 12M |
//              Xp 16M    (20M shorts = 40 MB)
// ---------------------------------------------------------------------------
extern "C" void kernel_launch(void* const* d_in, const int* in_sizes, int n_in,
                              void* d_out, int out_size, void* d_ws, size_t ws_size,
                              hipStream_t stream) {
    (void)in_sizes; (void)n_in; (void)out_size; (void)ws_size;

    const float* q  = (const float*)d_in[0];
    const float* k  = (const float*)d_in[1];
    const float* v  = (const float*)d_in[2];
    const float* Wq = (const float*)d_in[3];
    const float* bq = (const float*)d_in[4];
    const float* Wk = (const float*)d_in[5];
    const float* bk = (const float*)d_in[6];
    const float* Wv = (const float*)d_in[7];
    const float* bv = (const float*)d_in[8];
    const float* Wo = (const float*)d_in[9];
    const float* bo = (const float*)d_in[10];
    float* out = (float*)d_out;

    unsigned short* ws = (unsigned short*)d_ws;
    const size_t WSZ = (size_t)DM * DM;      // 1M shorts
    const size_t MSZ = (size_t)MR * DM;      // 4M shorts
    unsigned short* WtQ = ws;
    unsigned short* WtK = ws + WSZ;
    unsigned short* WtV = ws + 2 * WSZ;
    unsigned short* WtO = ws + 3 * WSZ;
    unsigned short* Qh  = ws + 4 * WSZ;
    unsigned short* Kh  = Qh + MSZ;
    unsigned short* Vtp = Kh + MSZ;
    unsigned short* Xp  = Vtp + MSZ;

    const dim3 blk(256);

    wt_prep_all<<<dim3(16, 4, 4), blk, 0, stream>>>(Wq, Wk, Wv, Wo, WtQ, WtK, WtV, WtO);

    gemm_qkv<<<dim3(8, 32, 3), blk, 0, stream>>>(q, k, v, WtQ, WtK, WtV,
                                                 bq, bk, bv, Qh, Kh, Vtp);

    attn_mfma<<<dim3(512), blk, 0, stream>>>(Qh, Kh, Vtp, Xp);

    gemm_out<<<dim3(16, 32), blk, 0, stream>>>(Xp, WtO, bo, out);
}